// Round 5
// baseline (255.723 us; speedup 1.0000x reference)
//
#include <hip/hip_runtime.h>

#define SEQ   8192
#define MAXP  2048
#define NEGI  (-1000000000.0f)

// out[i][j] = (0 <= i-j-1 <= MAXP-2) ? table[i-j-1] : NEG_INF
// 256 MiB fp32 output, 8 KiB table (L1-resident) -> pure store-BW-bound.
// Floor ~ 268 MB / 6.3 TB/s ~= 43 us.
__global__ __launch_bounds__(256) void rpe_kernel(const float* __restrict__ table,
                                                  float* __restrict__ out) {
    const int total_q = SEQ * (SEQ / 4);              // 16,777,216 float4 stores
    const int stride  = gridDim.x * blockDim.x;
    float4* __restrict__ out4 = reinterpret_cast<float4*>(out);

    const float4 neg4 = make_float4(NEGI, NEGI, NEGI, NEGI);

    for (int t = blockIdx.x * blockDim.x + threadIdx.x; t < total_q; t += stride) {
        const int i  = t >> 11;                 // row   (t / 2048 float4s per row)
        const int j  = (t & 2047) << 2;         // col base (4 elements per thread)
        const int d0 = i - j - 1;               // table index for element 0
        // elements k=0..3 have d = d0-k, valid iff d in [0, MAXP-2]

        if (d0 < 0 || d0 > MAXP + 1) {
            // All 4 elements masked (upper triangle + far band, ~94% of matrix).
            // Wave-uniform nearly everywhere (d0 spans 256 within a wave).
            out4[t] = neg4;
        } else {
            float4 v;
            v.x = ((unsigned)(d0    ) < (unsigned)(MAXP - 1)) ? table[d0    ] : NEGI;
            v.y = ((unsigned)(d0 - 1) < (unsigned)(MAXP - 1)) ? table[d0 - 1] : NEGI;
            v.z = ((unsigned)(d0 - 2) < (unsigned)(MAXP - 1)) ? table[d0 - 2] : NEGI;
            v.w = ((unsigned)(d0 - 3) < (unsigned)(MAXP - 1)) ? table[d0 - 3] : NEGI;
            out4[t] = v;
        }
    }
}

extern "C" void kernel_launch(void* const* d_in, const int* in_sizes, int n_in,
                              void* d_out, int out_size, void* d_ws, size_t ws_size,
                              hipStream_t stream) {
    const float* table = (const float*)d_in[0];
    float* out = (float*)d_out;
    // 4096 blocks x 256 threads (16 blocks/CU): each thread does 16 float4 stores.
    rpe_kernel<<<4096, 256, 0, stream>>>(table, out);
}